// Round 1
// baseline (388.069 us; speedup 1.0000x reference)
//
#include <hip/hip_runtime.h>
#include <hip/hip_bf16.h>

// Problem constants (from reference setup_inputs)
#define D     128
#define K0    50
#define NCOL  51      // output columns: 50 (centers0) + 1 (centers1)
#define NT    12      // 192 GEMM cols = 8 z_rot tiles + 4 cross tiles
#define NLT   10      // tiles resident in LDS per ks-step: 8 z_rot + 2 cross
#define TB    256     // batch rows per block (4 row-tiles per wave)

typedef __attribute__((ext_vector_type(4))) float  f32x4;
typedef __attribute__((ext_vector_type(8))) short  short8x;  // 8 bf16 in 4 VGPRs
// alignment-reduced vector types: out rows are 204 B, stores are only 4B-aligned
typedef f32x4 __attribute__((aligned(4))) f32x4u;
typedef __attribute__((ext_vector_type(2))) float f32x2;
typedef f32x2 __attribute__((aligned(4))) f32x2u;

__device__ inline short f2bf(float x) {
    __hip_bfloat16 h = __float2bfloat16(x);
    return __builtin_bit_cast(short, h);
}

// ---------------------------------------------------------------------------
// Setup: build G (128 x 192) in bf16 MFMA fragment order:
//   Gws[blk=(ks*12+nt)][lane][j] = G[ks*32+(lane>>4)*8+j][nt*16+(lane&15)]
//   tiles 0..7  : V itself (z_rot = z @ V), unscaled       (used as B operand)
//   tiles 8..11 : -2 * M, M[:,k] = V (beta . c_k)          (used as A operand:
//                 same storage reads as A[m=k][kdim=d] = -2*Mt[k][d])
// Block 48: cc[k] (beta-weighted center norms) + beta0 as float[128].
// ---------------------------------------------------------------------------
__global__ __launch_bounds__(128) void setup_kernel(
    const float* __restrict__ bw,   // [2][128]
    const float* __restrict__ V,    // [128][128]
    const float* __restrict__ c0,   // [50][128]
    const float* __restrict__ c1,   // [1][128]
    short* __restrict__ Gws,        // bf16 frag layout [48][64][8]
    float* __restrict__ ccws,       // [64] (51 used, rest zero)
    float* __restrict__ betaws)     // [128]
{
    const int blk = blockIdx.x;
    const int t   = threadIdx.x;
    __shared__ float beta0[D];
    __shared__ float Vt[D * 33];    // V[ks*32+d][e] transposed -> Vt[e*33+d]
    __shared__ float wct[D * 17];   // (beta.c)[k][e] transposed -> wct[e*17+k]

    if (t < D) {
        float b0 = bw[t], b1 = bw[D + t];
        beta0[t] = 1.0f / (1.0f + expf(b1 - b0));   // softmax over axis 0
    }
    __syncthreads();

    if (blk == 48) {                 // cc terms + beta float dump
        if (t < D) betaws[t] = beta0[t];
        if (t >= NCOL && t < 64) ccws[t] = 0.f;     // clean tail for f32x4 loads
        if (t < NCOL) {
            const float* cr = (t < K0) ? (c0 + (size_t)t * D) : c1;
            float s = 0.f;
            for (int e = 0; e < D; ++e) {
                float b = (t == K0) ? (1.0f - beta0[e]) : beta0[e];
                float cv = cr[e];
                s += b * cv * cv;
            }
            ccws[t] = s;
        }
        return;
    }

    const int kstep = blk / NT;      // 0..3
    const int ntile = blk % NT;      // 0..11
    const int lane  = t >> 1;
    const int jbase = (t & 1) * 4;
    const int nl    = lane & 15;

    if (ntile < 8) {                 // G col = V col: copy/convert
        const int n = ntile * 16 + nl;
        short* dst = Gws + ((size_t)(blk * 64 + lane)) * 8 + jbase;
        for (int jj = 0; jj < 4; ++jj) {
            int d = kstep * 32 + (lane >> 4) * 8 + jbase + jj;
            dst[jj] = f2bf(V[(size_t)d * D + n]);
        }
        return;
    }

    // cross tiles: stage V rows (transposed) and beta-weighted centers
    for (int i = t; i < 32 * D; i += 128) {
        int d = i >> 7, e = i & 127;              // consecutive t -> consecutive e
        Vt[e * 33 + d] = V[(size_t)(kstep * 32 + d) * D + e];
    }
    for (int i = t; i < 16 * D; i += 128) {
        int kl = i >> 7, e = i & 127;
        int k = (ntile - 8) * 16 + kl;
        float w = 0.f;
        if (k < K0)       w = beta0[e] * c0[(size_t)k * D + e];
        else if (k == K0) w = (1.0f - beta0[e]) * c1[e];
        wct[e * 17 + kl] = w;
    }
    __syncthreads();

    short res[4];
    for (int jj = 0; jj < 4; ++jj) {
        int dl = (lane >> 4) * 8 + jbase + jj;    // 0..31
        float s = 0.f;
        #pragma unroll 8
        for (int e = 0; e < D; ++e)
            s += Vt[e * 33 + dl] * wct[e * 17 + nl];   // bank-conflict-free
        res[jj] = f2bf(-2.0f * s);                     // fold -2x into G
    }
    short* dst = Gws + ((size_t)(blk * 64 + lane)) * 8 + jbase;
    for (int jj = 0; jj < 4; ++jj) dst[jj] = res[jj];
}

// ---------------------------------------------------------------------------
// Main: per block, 256 rows (4 row-tiles of 16 per wave).
//   z_rot tiles:  accr[nt] = mfma(zfrag, Gfrag)   -> C[row=batch][col=feat]
//   cross tiles:  accc[j]  = mfma(Gfrag, zfrag)   -> C[row=k][col=batch]
// Occupancy plan (this revision): LDS holds only 10 of 12 tiles per ks-step
// (40960 B exactly -> 4 blocks/CU = the whole 1024-block grid resident in ONE
// generation, killing the 25%-work drain tail the 48KB/3-block version had).
// Cross tiles j=2,3 (8 KB, loop-invariant) are read from global via L1/L2.
// cc[k] is folded into the cross accumulator init (fp32 reassociation only),
// freeing the 16 persistent ccreg VGPRs for the 128-VGPR/4-wave budget.
// ---------------------------------------------------------------------------
__global__ __launch_bounds__(256, 4) void main_kernel(
    const float* __restrict__ z,      // [B][128]
    const short* __restrict__ Gws,    // bf16 frag layout [48][64][8]
    const float* __restrict__ ccws,   // [64]
    const float* __restrict__ betaws, // [128]
    float* __restrict__ out)          // [B][51]
{
    __shared__ __align__(16) short Gs[4 * NLT * 64 * 8];  // 40960 B -> 4 blocks/CU

    const int t    = threadIdx.x;
    const int wave = t >> 6;
    const int lane = t & 63;
    const int c    = lane & 15;
    const int q    = lane >> 4;
    const size_t rowbase = (size_t)blockIdx.x * TB;

    // ---- stage LDS-resident G tiles (40 KB, L2-resident source) ----
    // LDS tile m = ks*10 + nt'  <-  global tile ks*12 + nt'   (nt' in 0..9)
    for (int i = t; i < 4 * NLT * 64; i += 256) {    // 2560 int4
        int m = i >> 6, r = i & 63;
        int g = (m / NLT) * NT + (m % NLT);
        ((int4*)Gs)[i] = ((const int4*)Gws)[g * 64 + r];
    }

    // ---- per-lane constants ----
    float breg[8];
    #pragma unroll
    for (int nt = 0; nt < 8; ++nt) breg[nt] = betaws[nt * 16 + c];
    __syncthreads();

    for (int rt = 0; rt < 4; ++rt) {
        const int rowloc = (wave * 4 + rt) * 16;
        const float* zrow = z + (rowbase + rowloc + c) * D;

        // z fragments (A and B views are the same layout); exact |z|^2 on the fly
        short8x zfrag[4];
        float nrm_p = 0.f;
        #pragma unroll
        for (int ks = 0; ks < 4; ++ks) {
            const float* p = zrow + ks * 32 + q * 8;
            f32x4 v0 = *(const f32x4*)p;
            f32x4 v1 = *(const f32x4*)(p + 4);
            nrm_p += v0.x*v0.x + v0.y*v0.y + v0.z*v0.z + v0.w*v0.w
                   + v1.x*v1.x + v1.y*v1.y + v1.z*v1.z + v1.w*v1.w;
            short8x a;
            a[0] = f2bf(v0.x); a[1] = f2bf(v0.y); a[2] = f2bf(v0.z); a[3] = f2bf(v0.w);
            a[4] = f2bf(v1.x); a[5] = f2bf(v1.y); a[6] = f2bf(v1.z); a[7] = f2bf(v1.w);
            zfrag[ks] = a;
        }

        f32x4 accr[8], accc[4];
        #pragma unroll
        for (int nt = 0; nt < 8; ++nt) accr[nt] = f32x4{0.f, 0.f, 0.f, 0.f};
        // cross accumulators start at cc[k]: lane(c,q) reg r holds k=j*16+q*4+r
        #pragma unroll
        for (int j = 0; j < 4; ++j)
            accc[j] = *(const f32x4*)(ccws + j * 16 + q * 4);

        #pragma unroll
        for (int ks = 0; ks < 4; ++ks) {
            #pragma unroll
            for (int nt = 0; nt < 8; ++nt) {
                short8x bfrg = *(const short8x*)&Gs[((ks * NLT + nt) * 64 + lane) * 8];
                accr[nt] = __builtin_amdgcn_mfma_f32_16x16x32_bf16(zfrag[ks], bfrg, accr[nt], 0, 0, 0);
            }
            #pragma unroll
            for (int j = 0; j < 2; ++j) {      // cross tiles 0,1 from LDS
                short8x afrg = *(const short8x*)&Gs[((ks * NLT + 8 + j) * 64 + lane) * 8];
                accc[j] = __builtin_amdgcn_mfma_f32_16x16x32_bf16(afrg, zfrag[ks], accc[j], 0, 0, 0);
            }
            #pragma unroll
            for (int j = 2; j < 4; ++j) {      // cross tiles 2,3 from global (L1-hot)
                short8x afrg = *(const short8x*)&Gws[((size_t)((ks * NT + 8 + j) * 64 + lane)) * 8];
                accc[j] = __builtin_amdgcn_mfma_f32_16x16x32_bf16(afrg, zfrag[ks], accc[j], 0, 0, 0);
            }
        }

        // ---- zz0 = sum beta0 * z_rot^2 over features (C: row=q*4+r, col=c) ----
        float qp[4] = {0.f, 0.f, 0.f, 0.f};
        #pragma unroll
        for (int nt = 0; nt < 8; ++nt) {
            #pragma unroll
            for (int r = 0; r < 4; ++r) {
                float y = accr[nt][r];
                qp[r] += breg[nt] * y * y;
            }
        }
        #pragma unroll
        for (int s = 1; s < 16; s <<= 1) {
            #pragma unroll
            for (int r = 0; r < 4; ++r) qp[r] += __shfl_xor(qp[r], s, 64);
        }
        // exact |z|^2: reduce over the 4 lanes sharing this c (q varies)
        float nrm = nrm_p + __shfl_xor(nrm_p, 16, 64);
        nrm += __shfl_xor(nrm, 32, 64);

        // redistribute zz0 to batch-row-c indexing: row c -> quad c>>2, reg c&3
        float tq[4];
        const int srcl = (c >> 2) * 16;
        #pragma unroll
        for (int r = 0; r < 4; ++r) tq[r] = __shfl(qp[r], srcl, 64);
        float zz0 = (c & 2) ? ((c & 1) ? tq[3] : tq[2])
                            : ((c & 1) ? tq[1] : tq[0]);

        // ---- dense stores: lane(c,q) -> row c, k = j*16+4q..+3 (cc already in accc) ----
        float* orow = out + (rowbase + rowloc + c) * NCOL;
        #pragma unroll
        for (int j = 0; j < 3; ++j) {          // k = 0..47: all use zz0
            f32x4 v;
            #pragma unroll
            for (int r = 0; r < 4; ++r) v[r] = zz0 + accc[j][r];
            *(f32x4u*)(orow + j * 16 + q * 4) = v;
        }
        if (q == 0) {                          // k = 48,49 (zz0) and 50 (zz1)
            f32x2 v2;
            v2.x = zz0 + accc[3][0];
            v2.y = zz0 + accc[3][1];
            *(f32x2u*)(orow + 48) = v2;
            orow[50] = (nrm - zz0) + accc[3][2];
        }
    }
}

extern "C" void kernel_launch(void* const* d_in, const int* in_sizes, int n_in,
                              void* d_out, int out_size, void* d_ws, size_t ws_size,
                              hipStream_t stream) {
    const float* z  = (const float*)d_in[0];
    const float* bw = (const float*)d_in[1];
    const float* V  = (const float*)d_in[2];
    const float* c0 = (const float*)d_in[3];
    const float* c1 = (const float*)d_in[4];
    float* out = (float*)d_out;

    short* Gws    = (short*)d_ws;                                  // 49152 B
    float* ccws   = (float*)((char*)d_ws + 48 * 64 * 8 * 2);       // 64 floats
    float* betaws = ccws + 64;                                     // 128 floats

    const int B = in_sizes[0] / D;   // 262144

    setup_kernel<<<49, 128, 0, stream>>>(bw, V, c0, c1, Gws, ccws, betaws);
    main_kernel<<<B / TB, 256, 0, stream>>>(z, Gws, ccws, betaws, out);
}

// Round 2
// 348.225 us; speedup vs baseline: 1.1144x; 1.1144x over previous
//
#include <hip/hip_runtime.h>
#include <hip/hip_bf16.h>

// Problem constants (from reference setup_inputs)
#define D     128
#define K0    50
#define NCOL  51      // output columns: 50 (centers0) + 1 (centers1)
#define NT    12      // 192 GEMM cols = 8 z_rot tiles + 4 cross tiles
#define NLT   10      // tiles resident in LDS per ks-step: 8 z_rot + 2 cross
#define TB    256     // batch rows per block (4 row-tiles per wave)

typedef __attribute__((ext_vector_type(4))) float  f32x4;
typedef __attribute__((ext_vector_type(8))) short  short8x;  // 8 bf16 in 4 VGPRs
// alignment-reduced vector types: out rows are 204 B, stores are only 4B-aligned
typedef f32x4 __attribute__((aligned(4))) f32x4u;
typedef __attribute__((ext_vector_type(2))) float f32x2;
typedef f32x2 __attribute__((aligned(4))) f32x2u;

__device__ inline short f2bf(float x) {
    __hip_bfloat16 h = __float2bfloat16(x);
    return __builtin_bit_cast(short, h);
}

// ---------------------------------------------------------------------------
// Setup: build G (128 x 192) in bf16 MFMA fragment order:
//   Gws[blk=(ks*12+nt)][lane][j] = G[ks*32+(lane>>4)*8+j][nt*16+(lane&15)]
//   tiles 0..7  : V itself (z_rot = z @ V), unscaled       (used as B operand)
//   tiles 8..11 : -2 * M, M[:,k] = V (beta . c_k)          (used as A operand)
// Block 48: cc[k] (beta-weighted center norms) + beta0 as float[128].
// ---------------------------------------------------------------------------
__global__ __launch_bounds__(128) void setup_kernel(
    const float* __restrict__ bw,   // [2][128]
    const float* __restrict__ V,    // [128][128]
    const float* __restrict__ c0,   // [50][128]
    const float* __restrict__ c1,   // [1][128]
    short* __restrict__ Gws,        // bf16 frag layout [48][64][8]
    float* __restrict__ ccws,       // [64] (51 used, rest zero)
    float* __restrict__ betaws)     // [128]
{
    const int blk = blockIdx.x;
    const int t   = threadIdx.x;
    __shared__ float beta0[D];
    __shared__ float Vt[D * 33];    // V[ks*32+d][e] transposed -> Vt[e*33+d]
    __shared__ float wct[D * 17];   // (beta.c)[k][e] transposed -> wct[e*17+k]

    if (t < D) {
        float b0 = bw[t], b1 = bw[D + t];
        beta0[t] = 1.0f / (1.0f + expf(b1 - b0));   // softmax over axis 0
    }
    __syncthreads();

    if (blk == 48) {                 // cc terms + beta float dump
        if (t < D) betaws[t] = beta0[t];
        if (t >= NCOL && t < 64) ccws[t] = 0.f;     // clean tail for f32x4 loads
        if (t < NCOL) {
            const float* cr = (t < K0) ? (c0 + (size_t)t * D) : c1;
            float s = 0.f;
            for (int e = 0; e < D; ++e) {
                float b = (t == K0) ? (1.0f - beta0[e]) : beta0[e];
                float cv = cr[e];
                s += b * cv * cv;
            }
            ccws[t] = s;
        }
        return;
    }

    const int kstep = blk / NT;      // 0..3
    const int ntile = blk % NT;      // 0..11
    const int lane  = t >> 1;
    const int jbase = (t & 1) * 4;
    const int nl    = lane & 15;

    if (ntile < 8) {                 // G col = V col: copy/convert
        const int n = ntile * 16 + nl;
        short* dst = Gws + ((size_t)(blk * 64 + lane)) * 8 + jbase;
        for (int jj = 0; jj < 4; ++jj) {
            int d = kstep * 32 + (lane >> 4) * 8 + jbase + jj;
            dst[jj] = f2bf(V[(size_t)d * D + n]);
        }
        return;
    }

    // cross tiles: stage V rows (transposed) and beta-weighted centers
    for (int i = t; i < 32 * D; i += 128) {
        int d = i >> 7, e = i & 127;              // consecutive t -> consecutive e
        Vt[e * 33 + d] = V[(size_t)(kstep * 32 + d) * D + e];
    }
    for (int i = t; i < 16 * D; i += 128) {
        int kl = i >> 7, e = i & 127;
        int k = (ntile - 8) * 16 + kl;
        float w = 0.f;
        if (k < K0)       w = beta0[e] * c0[(size_t)k * D + e];
        else if (k == K0) w = (1.0f - beta0[e]) * c1[e];
        wct[e * 17 + kl] = w;
    }
    __syncthreads();

    short res[4];
    for (int jj = 0; jj < 4; ++jj) {
        int dl = (lane >> 4) * 8 + jbase + jj;    // 0..31
        float s = 0.f;
        #pragma unroll 8
        for (int e = 0; e < D; ++e)
            s += Vt[e * 33 + dl] * wct[e * 17 + nl];   // bank-conflict-free
        res[jj] = f2bf(-2.0f * s);                     // fold -2x into G
    }
    short* dst = Gws + ((size_t)(blk * 64 + lane)) * 8 + jbase;
    for (int jj = 0; jj < 4; ++jj) dst[jj] = res[jj];
}

// ---------------------------------------------------------------------------
// Main: per block, 256 rows (4 row-tiles of 16 per wave).
// R2 register-budget restructure: at __launch_bounds__(256,4) the UNIFIED
// VGPR+AGPR cap is 128/wave (gfx950 unified RF). The old ks-outer loop kept
// accr[8]+accc[4]+zfrag[4] = 64 accumulator regs live -> spilled ~180 MB of
// scratch (R1: VGPR=64, WRITE 236 MB, 233 us). Fix: z_rot tiles are now
// NT-OUTER / KS-INNER — each accr chain (4 dependent MFMAs on one C, the
// standard K-chain pattern) completes and is folded into qp immediately,
// recycling its 4 regs. Live data drops to ~40 regs -> no spill at 4 blk/CU.
// LDS holds 10 of 12 tiles (40960 B exactly -> 4 blocks/CU = whole 1024-block
// grid resident in ONE generation, no drain tail). Cross tiles j=2,3 (8 KB,
// loop-invariant, L1-hot) are read from global. cc[k] folds into accc init.
// ---------------------------------------------------------------------------
__global__ __launch_bounds__(256, 4) void main_kernel(
    const float* __restrict__ z,      // [B][128]
    const short* __restrict__ Gws,    // bf16 frag layout [48][64][8]
    const float* __restrict__ ccws,   // [64]
    const float* __restrict__ betaws, // [128]
    float* __restrict__ out)          // [B][51]
{
    __shared__ __align__(16) short Gs[4 * NLT * 64 * 8];  // 40960 B -> 4 blocks/CU

    const int t    = threadIdx.x;
    const int wave = t >> 6;
    const int lane = t & 63;
    const int c    = lane & 15;
    const int q    = lane >> 4;
    const size_t rowbase = (size_t)blockIdx.x * TB;

    // ---- stage LDS-resident G tiles (40 KB, L2-resident source) ----
    // LDS tile m = ks*10 + nt'  <-  global tile ks*12 + nt'   (nt' in 0..9)
    for (int i = t; i < 4 * NLT * 64; i += 256) {    // 2560 int4
        int m = i >> 6, r = i & 63;
        int g = (m / NLT) * NT + (m % NLT);
        ((int4*)Gs)[i] = ((const int4*)Gws)[g * 64 + r];
    }

    // ---- per-lane constants ----
    float breg[8];
    #pragma unroll
    for (int nt = 0; nt < 8; ++nt) breg[nt] = betaws[nt * 16 + c];
    __syncthreads();

    for (int rt = 0; rt < 4; ++rt) {
        const int rowloc = (wave * 4 + rt) * 16;
        const float* zrow = z + (rowbase + rowloc + c) * D;

        // z fragments (A and B views are the same layout); exact |z|^2 on the fly
        short8x zfrag[4];
        float nrm_p = 0.f;
        #pragma unroll
        for (int ks = 0; ks < 4; ++ks) {
            const float* p = zrow + ks * 32 + q * 8;
            f32x4 v0 = *(const f32x4*)p;
            f32x4 v1 = *(const f32x4*)(p + 4);
            nrm_p += v0.x*v0.x + v0.y*v0.y + v0.z*v0.z + v0.w*v0.w
                   + v1.x*v1.x + v1.y*v1.y + v1.z*v1.z + v1.w*v1.w;
            short8x a;
            a[0] = f2bf(v0.x); a[1] = f2bf(v0.y); a[2] = f2bf(v0.z); a[3] = f2bf(v0.w);
            a[4] = f2bf(v1.x); a[5] = f2bf(v1.y); a[6] = f2bf(v1.z); a[7] = f2bf(v1.w);
            zfrag[ks] = a;
        }

        // cross accumulators start at cc[k]: lane(c,q) reg r holds k=j*16+q*4+r
        f32x4 accc[4];
        #pragma unroll
        for (int j = 0; j < 4; ++j)
            accc[j] = *(const f32x4*)(ccws + j * 16 + q * 4);

        // ---- cross tiles, j-outer / ks-inner (K-chained accumulate) ----
        #pragma unroll
        for (int j = 0; j < 2; ++j) {          // tiles 8,9 from LDS
            #pragma unroll
            for (int ks = 0; ks < 4; ++ks) {
                short8x afrg = *(const short8x*)&Gs[((ks * NLT + 8 + j) * 64 + lane) * 8];
                accc[j] = __builtin_amdgcn_mfma_f32_16x16x32_bf16(afrg, zfrag[ks], accc[j], 0, 0, 0);
            }
        }
        #pragma unroll
        for (int j = 2; j < 4; ++j) {          // tiles 10,11 from global (L1-hot)
            #pragma unroll
            for (int ks = 0; ks < 4; ++ks) {
                short8x afrg = *(const short8x*)&Gws[((size_t)((ks * NT + 8 + j) * 64 + lane)) * 8];
                accc[j] = __builtin_amdgcn_mfma_f32_16x16x32_bf16(afrg, zfrag[ks], accc[j], 0, 0, 0);
            }
        }

        // ---- z_rot tiles, nt-outer / ks-inner; fold into qp immediately ----
        // (C layout: col=c=feature-within-tile, row=q*4+r=batch-row)
        float qp[4] = {0.f, 0.f, 0.f, 0.f};
        #pragma unroll
        for (int nt = 0; nt < 8; ++nt) {
            f32x4 acc = f32x4{0.f, 0.f, 0.f, 0.f};
            #pragma unroll
            for (int ks = 0; ks < 4; ++ks) {
                short8x bfrg = *(const short8x*)&Gs[((ks * NLT + nt) * 64 + lane) * 8];
                acc = __builtin_amdgcn_mfma_f32_16x16x32_bf16(zfrag[ks], bfrg, acc, 0, 0, 0);
            }
            #pragma unroll
            for (int r = 0; r < 4; ++r) {
                float y = acc[r];
                qp[r] += breg[nt] * y * y;
            }
        }

        // ---- zz0: reduce over the 16 c-lanes ----
        #pragma unroll
        for (int s = 1; s < 16; s <<= 1) {
            #pragma unroll
            for (int r = 0; r < 4; ++r) qp[r] += __shfl_xor(qp[r], s, 64);
        }
        // exact |z|^2: reduce over the 4 lanes sharing this c (q varies)
        float nrm = nrm_p + __shfl_xor(nrm_p, 16, 64);
        nrm += __shfl_xor(nrm, 32, 64);

        // redistribute zz0 to batch-row-c indexing: row c -> quad c>>2, reg c&3
        float tq[4];
        const int srcl = (c >> 2) * 16;
        #pragma unroll
        for (int r = 0; r < 4; ++r) tq[r] = __shfl(qp[r], srcl, 64);
        float zz0 = (c & 2) ? ((c & 1) ? tq[3] : tq[2])
                            : ((c & 1) ? tq[1] : tq[0]);

        // ---- dense stores: lane(c,q) -> row c, k = j*16+4q..+3 (cc already in accc) ----
        float* orow = out + (rowbase + rowloc + c) * NCOL;
        #pragma unroll
        for (int j = 0; j < 3; ++j) {          // k = 0..47: all use zz0
            f32x4 v;
            #pragma unroll
            for (int r = 0; r < 4; ++r) v[r] = zz0 + accc[j][r];
            *(f32x4u*)(orow + j * 16 + q * 4) = v;
        }
        if (q == 0) {                          // k = 48,49 (zz0) and 50 (zz1)
            f32x2 v2;
            v2.x = zz0 + accc[3][0];
            v2.y = zz0 + accc[3][1];
            *(f32x2u*)(orow + 48) = v2;
            orow[50] = (nrm - zz0) + accc[3][2];
        }
    }
}

extern "C" void kernel_launch(void* const* d_in, const int* in_sizes, int n_in,
                              void* d_out, int out_size, void* d_ws, size_t ws_size,
                              hipStream_t stream) {
    const float* z  = (const float*)d_in[0];
    const float* bw = (const float*)d_in[1];
    const float* V  = (const float*)d_in[2];
    const float* c0 = (const float*)d_in[3];
    const float* c1 = (const float*)d_in[4];
    float* out = (float*)d_out;

    short* Gws    = (short*)d_ws;                                  // 49152 B
    float* ccws   = (float*)((char*)d_ws + 48 * 64 * 8 * 2);       // 64 floats
    float* betaws = ccws + 64;                                     // 128 floats

    const int B = in_sizes[0] / D;   // 262144

    setup_kernel<<<49, 128, 0, stream>>>(bw, V, c0, c1, Gws, ccws, betaws);
    main_kernel<<<B / TB, 256, 0, stream>>>(z, Gws, ccws, betaws, out);
}

// Round 5
// 311.464 us; speedup vs baseline: 1.2460x; 1.1180x over previous
//
#include <hip/hip_runtime.h>
#include <hip/hip_bf16.h>

// Problem constants (from reference setup_inputs)
#define D     128
#define K0    50
#define NCOL  51      // output columns: 50 (centers0) + 1 (centers1)
#define NT    12      // 192 GEMM cols = 8 z_rot tiles + 4 cross tiles
#define TB    128     // batch rows per block (2 row-tiles per wave; R5: halved
                      // to cut the drain-tail from 33% to 11% at 3 blocks/CU)

typedef __attribute__((ext_vector_type(4))) float  f32x4;
typedef __attribute__((ext_vector_type(8))) short  short8x;  // 8 bf16 in 4 VGPRs
// alignment-reduced vector types: out rows are 204 B, stores are only 4B-aligned
typedef f32x4 __attribute__((aligned(4))) f32x4u;
typedef __attribute__((ext_vector_type(2))) float f32x2;
typedef f32x2 __attribute__((aligned(4))) f32x2u;

__device__ inline short f2bf(float x) {
    __hip_bfloat16 h = __float2bfloat16(x);
    return __builtin_bit_cast(short, h);
}

// ---------------------------------------------------------------------------
// Setup: build G (128 x 192) in bf16 MFMA fragment order:
//   Gws[blk=(ks*12+nt)][lane][j] = G[ks*32+(lane>>4)*8+j][nt*16+(lane&15)]
//   tiles 0..7  : V * diag(sqrt(beta0))  (z_rot pre-scaled so zz0 = sum y^2;
//                 kills the per-lane breg[8] in main)
//   tiles 8..11 : -2 * M, M[:,k] = V (beta . c_k)  (used as A operand)
// Block 48: cc[k] (beta-weighted center norms, [64] zero-padded) + beta0 dump.
// ---------------------------------------------------------------------------
__global__ __launch_bounds__(128) void setup_kernel(
    const float* __restrict__ bw,   // [2][128]
    const float* __restrict__ V,    // [128][128]
    const float* __restrict__ c0,   // [50][128]
    const float* __restrict__ c1,   // [1][128]
    short* __restrict__ Gws,        // bf16 frag layout [48][64][8]
    float* __restrict__ ccws,       // [64] (51 used, rest zero)
    float* __restrict__ betaws)     // [128]
{
    const int blk = blockIdx.x;
    const int t   = threadIdx.x;
    __shared__ float beta0[D];
    __shared__ float Vt[D * 33];    // V[ks*32+d][e] transposed -> Vt[e*33+d]
    __shared__ float wct[D * 17];   // (beta.c)[k][e] transposed -> wct[e*17+k]

    if (t < D) {
        float b0 = bw[t], b1 = bw[D + t];
        beta0[t] = 1.0f / (1.0f + expf(b1 - b0));   // softmax over axis 0
    }
    __syncthreads();

    if (blk == 48) {                 // cc terms + beta float dump
        if (t < D) betaws[t] = beta0[t];
        if (t >= NCOL && t < 64) ccws[t] = 0.f;     // clean tail for f32x4 loads
        if (t < NCOL) {
            const float* cr = (t < K0) ? (c0 + (size_t)t * D) : c1;
            float s = 0.f;
            for (int e = 0; e < D; ++e) {
                float b = (t == K0) ? (1.0f - beta0[e]) : beta0[e];
                float cv = cr[e];
                s += b * cv * cv;
            }
            ccws[t] = s;
        }
        return;
    }

    const int kstep = blk / NT;      // 0..3
    const int ntile = blk % NT;      // 0..11
    const int lane  = t >> 1;
    const int jbase = (t & 1) * 4;
    const int nl    = lane & 15;

    if (ntile < 8) {                 // G col = V col * sqrt(beta0[col])
        const int n = ntile * 16 + nl;
        const float sb = sqrtf(beta0[n]);
        short* dst = Gws + ((size_t)(blk * 64 + lane)) * 8 + jbase;
        for (int jj = 0; jj < 4; ++jj) {
            int d = kstep * 32 + (lane >> 4) * 8 + jbase + jj;
            dst[jj] = f2bf(V[(size_t)d * D + n] * sb);
        }
        return;
    }

    // cross tiles: stage V rows (transposed) and beta-weighted centers
    for (int i = t; i < 32 * D; i += 128) {
        int d = i >> 7, e = i & 127;              // consecutive t -> consecutive e
        Vt[e * 33 + d] = V[(size_t)(kstep * 32 + d) * D + e];
    }
    for (int i = t; i < 16 * D; i += 128) {
        int kl = i >> 7, e = i & 127;
        int k = (ntile - 8) * 16 + kl;
        float w = 0.f;
        if (k < K0)       w = beta0[e] * c0[(size_t)k * D + e];
        else if (k == K0) w = (1.0f - beta0[e]) * c1[e];
        wct[e * 17 + kl] = w;
    }
    __syncthreads();

    short res[4];
    for (int jj = 0; jj < 4; ++jj) {
        int dl = (lane >> 4) * 8 + jbase + jj;    // 0..31
        float s = 0.f;
        #pragma unroll 8
        for (int e = 0; e < D; ++e)
            s += Vt[e * 33 + dl] * wct[e * 17 + nl];   // bank-conflict-free
        res[jj] = f2bf(-2.0f * s);                     // fold -2x into G
    }
    short* dst = Gws + ((size_t)(blk * 64 + lane)) * 8 + jbase;
    for (int jj = 0; jj < 4; ++jj) dst[jj] = res[jj];
}

// ---------------------------------------------------------------------------
// Main: per block, 128 rows (2 row-tiles of 16 per wave).
// R5 rationale: the (256,4)/40KB experiments spilled ~150MB (unified 128-reg
// cap split 64 arch + 64 AGPR; scheduler-hoisted ds_read fragments blew the
// arch half). Revert to the R0-proven regime — 48KB LDS, (256,3), ~170-reg
// budget, NO sched_barrier, no spill — and fix R0's actual problem (the 33%
// drain tail at grid=1024, 3 blocks/CU) by halving the work quantum:
// TB=128, grid=2048 -> ceil(2048/768)=3 half-size generations = 89% eff.
// Register diet kept from R2/R3: sqrt(beta0) folded into G (no breg[8]),
// cc[k] folded into the accc MFMA C-init (no ccreg[16]), nt-outer/ks-inner
// z_rot loop (4-reg accumulator recycled per tile).
// ---------------------------------------------------------------------------
__global__ __launch_bounds__(256, 3) void main_kernel(
    const float* __restrict__ z,      // [B][128]
    const short* __restrict__ Gws,    // bf16 frag layout [48][64][8]
    const float* __restrict__ ccws,   // [64]
    const float* __restrict__ betaws, // [128] (unused; beta folded into G)
    float* __restrict__ out)          // [B][51]
{
    __shared__ __align__(16) short Gs[48 * 64 * 8];  // 49152 B -> 3 blocks/CU

    const int t    = threadIdx.x;
    const int wave = t >> 6;
    const int lane = t & 63;
    const int c    = lane & 15;
    const int q    = lane >> 4;
    const size_t rowbase = (size_t)blockIdx.x * TB;

    // ---- stage G (48 KB, L2-resident source) ----
    for (int i = t; i < 48 * 64 * 8 / 8; i += 256)
        ((int4*)Gs)[i] = ((const int4*)Gws)[i];
    __syncthreads();

    for (int rt = 0; rt < 2; ++rt) {
        const int rowloc = (wave * 2 + rt) * 16;
        const float* zrow = z + (rowbase + rowloc + c) * D;

        // z fragments (A and B views are the same layout); exact |z|^2 on the fly
        short8x zfrag[4];
        float nrm_p = 0.f;
        #pragma unroll
        for (int ks = 0; ks < 4; ++ks) {
            const float* p = zrow + ks * 32 + q * 8;
            f32x4 v0 = *(const f32x4*)p;
            f32x4 v1 = *(const f32x4*)(p + 4);
            nrm_p += v0.x*v0.x + v0.y*v0.y + v0.z*v0.z + v0.w*v0.w
                   + v1.x*v1.x + v1.y*v1.y + v1.z*v1.z + v1.w*v1.w;
            short8x a;
            a[0] = f2bf(v0.x); a[1] = f2bf(v0.y); a[2] = f2bf(v0.z); a[3] = f2bf(v0.w);
            a[4] = f2bf(v1.x); a[5] = f2bf(v1.y); a[6] = f2bf(v1.z); a[7] = f2bf(v1.w);
            zfrag[ks] = a;
        }

        // cross accumulators start at cc[k]: lane(c,q) reg r holds k=j*16+q*4+r
        f32x4 accc[4];
        #pragma unroll
        for (int j = 0; j < 4; ++j)
            accc[j] = *(const f32x4*)(ccws + j * 16 + q * 4);

        // ---- cross tiles, j-outer / ks-inner (K-chained accumulate) ----
        #pragma unroll
        for (int j = 0; j < 4; ++j) {
            #pragma unroll
            for (int ks = 0; ks < 4; ++ks) {
                short8x afrg = *(const short8x*)&Gs[((ks * NT + 8 + j) * 64 + lane) * 8];
                accc[j] = __builtin_amdgcn_mfma_f32_16x16x32_bf16(afrg, zfrag[ks], accc[j], 0, 0, 0);
            }
        }

        // ---- z_rot tiles (sqrt(beta) pre-folded), nt-outer / ks-inner ----
        // (C layout: col=c=feature-within-tile, row=q*4+r=batch-row)
        float qp[4] = {0.f, 0.f, 0.f, 0.f};
        #pragma unroll
        for (int nt = 0; nt < 8; ++nt) {
            f32x4 acc = f32x4{0.f, 0.f, 0.f, 0.f};
            #pragma unroll
            for (int ks = 0; ks < 4; ++ks) {
                short8x bfrg = *(const short8x*)&Gs[((ks * NT + nt) * 64 + lane) * 8];
                acc = __builtin_amdgcn_mfma_f32_16x16x32_bf16(zfrag[ks], bfrg, acc, 0, 0, 0);
            }
            #pragma unroll
            for (int r = 0; r < 4; ++r) {
                float y = acc[r];
                qp[r] += y * y;                // beta already inside G
            }
        }

        // ---- zz0: reduce over the 16 c-lanes ----
        #pragma unroll
        for (int s = 1; s < 16; s <<= 1) {
            #pragma unroll
            for (int r = 0; r < 4; ++r) qp[r] += __shfl_xor(qp[r], s, 64);
        }
        // exact |z|^2: reduce over the 4 lanes sharing this c (q varies)
        float nrm = nrm_p + __shfl_xor(nrm_p, 16, 64);
        nrm += __shfl_xor(nrm, 32, 64);

        // redistribute zz0 to batch-row-c indexing: row c -> quad c>>2, reg c&3
        float tq[4];
        const int srcl = (c >> 2) * 16;
        #pragma unroll
        for (int r = 0; r < 4; ++r) tq[r] = __shfl(qp[r], srcl, 64);
        float zz0 = (c & 2) ? ((c & 1) ? tq[3] : tq[2])
                            : ((c & 1) ? tq[1] : tq[0]);

        // ---- dense stores: lane(c,q) -> row c, k = j*16+4q..+3 (cc already in accc) ----
        float* orow = out + (rowbase + rowloc + c) * NCOL;
        #pragma unroll
        for (int j = 0; j < 3; ++j) {          // k = 0..47: all use zz0
            f32x4 v;
            #pragma unroll
            for (int r = 0; r < 4; ++r) v[r] = zz0 + accc[j][r];
            *(f32x4u*)(orow + j * 16 + q * 4) = v;
        }
        if (q == 0) {                          // k = 48,49 (zz0) and 50 (zz1)
            f32x2 v2;
            v2.x = zz0 + accc[3][0];
            v2.y = zz0 + accc[3][1];
            *(f32x2u*)(orow + 48) = v2;
            orow[50] = (nrm - zz0) + accc[3][2];
        }
    }
}

extern "C" void kernel_launch(void* const* d_in, const int* in_sizes, int n_in,
                              void* d_out, int out_size, void* d_ws, size_t ws_size,
                              hipStream_t stream) {
    const float* z  = (const float*)d_in[0];
    const float* bw = (const float*)d_in[1];
    const float* V  = (const float*)d_in[2];
    const float* c0 = (const float*)d_in[3];
    const float* c1 = (const float*)d_in[4];
    float* out = (float*)d_out;

    short* Gws    = (short*)d_ws;                                  // 49152 B
    float* ccws   = (float*)((char*)d_ws + 48 * 64 * 8 * 2);       // 64 floats
    float* betaws = ccws + 64;                                     // 128 floats

    const int B = in_sizes[0] / D;   // 262144

    setup_kernel<<<49, 128, 0, stream>>>(bw, V, c0, c1, Gws, ccws, betaws);
    main_kernel<<<B / TB, 256, 0, stream>>>(z, Gws, ccws, betaws, out);
}